// Round 5
// baseline (263.753 us; speedup 1.0000x reference)
//
#include <hip/hip_runtime.h>
#include <math.h>

#define NATOMS 10000
#define NEDGES 320000
#define NBINS  (NATOMS * 4)     // bin = atom*4 + species (bin a*4+3 always empty)
#define RC_F 5.0f
#define PI_F 3.14159265358979323846f

// ---- workspace layout (in floats; all segments 16B-aligned) ----
#define WS_SEMB   0         // 12 floats: semb[t][s]
#define WS_GTOT   12        // 1 int: global allocation cursor
#define WS_CNT    16        // NBINS ints
#define WS_OFFS   40016     // NBINS ints (offs[4a+3] = end of atom a's run)
#define WS_CURSOR 80016     // NBINS ints
#define WS_EIDX   120016    // NEDGES ints: per-bin edge index lists
#define WS_STAGE  440016    // NEDGES*52 floats, record stride 208B, slot = edge id

// multinomial term tables (global component index 0..34)
__device__ __constant__ int   d_PWA[35] = {0, 0,0,1, 0,0,0,1,1,2, 0,0,0,0,1,1,1,2,2,3, 0,0,0,0,0,1,1,1,1,2,2,2,3,3,4};
__device__ __constant__ int   d_PWB[35] = {0, 0,1,0, 0,1,2,0,1,0, 0,1,2,3,0,1,2,0,1,0, 0,1,2,3,4,0,1,2,3,0,1,2,0,1,0};
__device__ __constant__ int   d_PWC[35] = {0, 1,0,0, 2,1,0,1,0,0, 3,2,1,0,2,1,0,1,0,0, 4,3,2,1,0,3,2,1,0,2,1,0,1,0,0};
__device__ __constant__ float d_NM[35]  = {1.f, 1.f,1.f,1.f, 1.f,2.f,1.f,2.f,2.f,1.f,
                                           1.f,3.f,3.f,1.f,3.f,6.f,3.f,3.f,3.f,1.f,
                                           1.f,4.f,6.f,4.f,1.f,4.f,12.f,12.f,4.f,6.f,12.f,6.f,4.f,4.f,1.f};
__device__ __constant__ int   d_LBLK[35]= {0, 1,1,1, 2,2,2,2,2,2, 3,3,3,3,3,3,3,3,3,3, 4,4,4,4,4,4,4,4,4,4,4,4,4,4,4};
__device__ __constant__ int   d_L6[6]   = {0,1,4,10,20,35};

__device__ __forceinline__ float siluf(float x) { return x / (1.0f + __expf(-x)); }

__device__ __forceinline__ float psel(float x, int p) {
  float x2 = x * x;
  float r = 1.0f;
  r = (p == 1) ? x : r;
  r = (p == 2) ? x2 : r;
  r = (p == 3) ? x2 * x : r;
  r = (p == 4) ? x2 * x2 : r;
  return r;
}

// ---------------- k_init ----------------
__global__ void k_init(const float* __restrict__ Ws1, const float* __restrict__ bs1,
                       const float* __restrict__ Ws2, const float* __restrict__ bs2,
                       float* __restrict__ ws)
{
  int tid = blockIdx.x * blockDim.x + threadIdx.x;
  int* cnt = (int*)(ws + WS_CNT);
  if (tid < NBINS) cnt[tid] = 0;
  if (tid == 0) *(int*)(ws + WS_GTOT) = 0;
  if (tid < 12) {
    int t = tid >> 2, s = tid & 3;
    float acc = bs2[s];
    for (int j = 0; j < 16; j++) acc += tanhf(Ws1[t * 16 + j] + bs1[j]) * Ws2[j * 4 + s];
    ws[WS_SEMB + tid] = acc;
  }
}

// ---------------- k_hist ----------------
__global__ void k_hist(const int* __restrict__ first_atom, const int* __restrict__ second_atom,
                       const int* __restrict__ species, float* __restrict__ ws)
{
  int e = blockIdx.x * blockDim.x + threadIdx.x;
  if (e < NEDGES) {
    int* cnt = (int*)(ws + WS_CNT);
    int bin = first_atom[e] * 4 + species[second_atom[e]];
    atomicAdd(&cnt[bin], 1);
  }
}

// ---------------- k_alloc: decentralized slot allocation (order-free) ----------------
__global__ __launch_bounds__(256) void k_alloc(float* __restrict__ ws)
{
  const int4* cnt4 = (const int4*)(ws + WS_CNT);
  int4* offs4   = (int4*)(ws + WS_OFFS);
  int4* cursor4 = (int4*)(ws + WS_CURSOR);
  int* gtot = (int*)(ws + WS_GTOT);
  __shared__ int wsum[4];
  __shared__ int sbase;
  int tid = threadIdx.x;
  int lane = tid & 63, wv = tid >> 6;
  int a = blockIdx.x * 256 + tid;
  bool live = (a < NATOMS);
  int4 c = live ? cnt4[a] : make_int4(0, 0, 0, 0);
  int s = c.x + c.y + c.z + c.w;
  int inc = s;
  #pragma unroll
  for (int d = 1; d < 64; d <<= 1) {
    int v = __shfl_up(inc, d, 64);
    if (lane >= d) inc += v;
  }
  if (lane == 63) wsum[wv] = inc;
  __syncthreads();
  if (tid == 0) {
    int btot = wsum[0] + wsum[1] + wsum[2] + wsum[3];
    sbase = atomicAdd(gtot, btot);
  }
  __syncthreads();
  int woff = sbase;
  for (int w = 0; w < wv; w++) woff += wsum[w];
  int o0 = woff + inc - s;
  if (live) {
    int4 o;
    o.x = o0;
    o.y = o.x + c.x;
    o.z = o.y + c.y;
    o.w = o.z + c.z;
    offs4[a] = o;
    cursor4[a] = o;
  }
}

// ---------------- k_scatter: build per-bin edge-index lists (4B per edge) ----------------
__global__ void k_scatter(const int* __restrict__ first_atom, const int* __restrict__ second_atom,
                          const int* __restrict__ species, float* __restrict__ ws)
{
  int e = blockIdx.x * blockDim.x + threadIdx.x;
  if (e < NEDGES) {
    int* cursor = (int*)(ws + WS_CURSOR);
    int* eidx   = (int*)(ws + WS_EIDX);
    int bin = first_atom[e] * 4 + species[second_atom[e]];
    int pos = atomicAdd(&cursor[bin], 1);
    eidx[pos] = e;
  }
}

// ---------------- k_edge: dense per-edge MLP, record stored at OWN slot e ----------------
// No atomics, no index gathers: pure compute + dense sequential 208B stores.
__global__ __launch_bounds__(256) void k_edge(
    const float* __restrict__ rij,
    const float* __restrict__ Wr1, const float* __restrict__ br1,
    const float* __restrict__ Wr2, const float* __restrict__ br2,
    float* __restrict__ ws)
{
  int e = blockIdx.x * 256 + threadIdx.x;
  if (e >= NEDGES) return;
  float* stage = ws + WS_STAGE;

  float x = rij[e * 3 + 0], y = rij[e * 3 + 1], z = rij[e * 3 + 2];
  float d = sqrtf(x * x + y * y + z * z + 1e-12f);
  float invd = 1.0f / d;
  float fc = (d < RC_F) ? 0.5f * (__cosf(PI_F * d / RC_F) + 1.0f) : 0.0f;

  float bes[8];
  float sq = sqrtf(2.0f / RC_F);
  #pragma unroll
  for (int k = 0; k < 8; k++) bes[k] = sq * __sinf((float)(k + 1) * (PI_F / RC_F) * d) * invd;

  // layer 1: 8 -> 64.  Wr1 [k=8][j=64], wave-uniform index -> s_load
  float h1[64];
  #pragma unroll
  for (int j4 = 0; j4 < 16; j4++) {
    float acc[4];
    #pragma unroll
    for (int u = 0; u < 4; u++) acc[u] = br1[j4 * 4 + u];
    #pragma unroll
    for (int k = 0; k < 8; k++) {
      #pragma unroll
      for (int u = 0; u < 4; u++) acc[u] += bes[k] * Wr1[k * 64 + j4 * 4 + u];
    }
    #pragma unroll
    for (int u = 0; u < 4; u++) h1[j4 * 4 + u] = siluf(acc[u]);
  }

  float* eb = stage + (size_t)e * 52;

  // layer 2: 64 -> 48.  Wr2 [k=64][j2=48], wave-uniform index -> s_load
  for (int j4 = 0; j4 < 12; j4++) {
    float acc[4];
    #pragma unroll
    for (int u = 0; u < 4; u++) acc[u] = br2[j4 * 4 + u];
    #pragma unroll
    for (int k = 0; k < 64; k++) {
      #pragma unroll
      for (int u = 0; u < 4; u++) acc[u] += h1[k] * Wr2[k * 48 + j4 * 4 + u];
    }
    float v0 = siluf(acc[0]) * fc, v1 = siluf(acc[1]) * fc;
    float v2 = siluf(acc[2]) * fc, v3 = siluf(acc[3]) * fc;
    *(float4*)(eb + j4 * 4) = make_float4(v0, v1, v2, v3);
  }
  *(float4*)(eb + 48) = make_float4(x * invd, y * invd, z * invd, 0.0f);
}

// ---------------- k_atom: TWO WAVES per atom, eidx-indirect, one barrier ----------------
__global__ __launch_bounds__(128) void k_atom(
    const float* __restrict__ ws,
    const float* __restrict__ Wa1, const float* __restrict__ ba1,
    const float* __restrict__ Wa2, const float* __restrict__ ba2,
    const float* __restrict__ Wa3, const float* __restrict__ ba3,
    float* __restrict__ out)
{
  __shared__ __align__(16) float sGp[2][864];   // per-wave partial G[t][r][36] (col 35 = G0)
  __shared__ float sFeat[192];
  __shared__ float sH[64];
  int tid = threadIdx.x;
  int lane = tid & 63, wv = tid >> 6;
  int a = blockIdx.x;

  const int* offs = (const int*)(ws + WS_OFFS);
  const int* eidx = (const int*)(ws + WS_EIDX);
  const float* stage = ws + WS_STAGE;
  int4 o = ((const int4*)offs)[a];
  int o0 = o.x, o1 = o.y, o2 = o.z, o3 = o.w;

  const int c = lane;
  bool isc = (c < 35);
  int pa = 0, pb = 0, pcw = 0, lb = 0;
  if (isc) { pa = d_PWA[c]; pb = d_PWB[c]; pcw = d_PWC[c]; lb = d_LBLK[c]; }
  int rdir = lane - 35;
  bool isd = (rdir >= 0) && (rdir < 8);

  float gc[3][8];
  #pragma unroll
  for (int t2 = 0; t2 < 3; t2++)
    #pragma unroll
    for (int r = 0; r < 8; r++) gc[t2][r] = 0.0f;
  float g0[3] = {0.0f, 0.0f, 0.0f};

  // prefetch first 64 edge indices (coalesced); distribute by readlane later
  int curch = 0;
  int pp0 = o0 + lane;
  int pre = eidx[pp0 < o3 ? pp0 : (NEDGES - 1)];

#define RUN(T, LO, HI)                                                        \
  for (int i = (LO) + wv; i < (HI); i += 2) {                                 \
    int rel = i - o0;                                                         \
    int ch = rel >> 6;                                                        \
    if (ch != curch) {                                                        \
      curch = ch;                                                             \
      int pp = o0 + (ch << 6) + lane;                                         \
      pre = eidx[pp < o3 ? pp : (NEDGES - 1)];                                \
    }                                                                         \
    int idx = __shfl(pre, rel & 63, 64);                                      \
    const float* eb = stage + (size_t)idx * 52;                               \
    if (isc) {                                                                \
      float4 rt = *(const float4*)(eb + 48);                                  \
      float comp = psel(rt.x, pa) * psel(rt.y, pb) * psel(rt.z, pcw);         \
      float4 Ra = *(const float4*)(eb + 8 + 8 * lb);                          \
      float4 Rb = *(const float4*)(eb + 12 + 8 * lb);                         \
      gc[T][0] += comp * Ra.x; gc[T][1] += comp * Ra.y;                       \
      gc[T][2] += comp * Ra.z; gc[T][3] += comp * Ra.w;                       \
      gc[T][4] += comp * Rb.x; gc[T][5] += comp * Rb.y;                       \
      gc[T][6] += comp * Rb.z; gc[T][7] += comp * Rb.w;                       \
    } else if (isd) {                                                         \
      g0[T] += eb[rdir];                                                      \
    }                                                                         \
  }

  RUN(0, o0, o1)
  RUN(1, o1, o2)
  RUN(2, o2, o3)
#undef RUN

  // write this wave's partial G to its LDS buffer (fully covers all 864 slots)
  float* sG = sGp[wv];
  if (isc) {
    #pragma unroll
    for (int t2 = 0; t2 < 3; t2++)
      #pragma unroll
      for (int r = 0; r < 8; r++) sG[(t2 * 8 + r) * 36 + c] = gc[t2][r];
  } else if (isd) {
    #pragma unroll
    for (int t2 = 0; t2 < 3; t2++) sG[(t2 * 8 + rdir) * 36 + 35] = g0[t2];
  } else {
    // lanes 43..63: fill nothing (all 864 slots covered by isc/isd lanes)
  }
  __syncthreads();

  if (wv == 0) {
    // contraction: lane owns feats {lane, lane+64, lane+128}; f=(blk*8+rr)*4+s
    int s = lane & 3;
    float se0 = ws[WS_SEMB + s], se1 = ws[WS_SEMB + 4 + s], se2 = ws[WS_SEMB + 8 + s];
    #define GSUM(off) (sGp[0][off] + sGp[1][off])
    float fout[3];
    #pragma unroll
    for (int u = 0; u < 3; u++) {
      int f = lane + 64 * u;
      int blk = f >> 5, rr = (f >> 2) & 7;
      float acc;
      if (blk == 0) {
        acc = se0 * GSUM((0 + rr) * 36 + 35) + se1 * GSUM((8 + rr) * 36 + 35) + se2 * GSUM((16 + rr) * 36 + 35);
      } else {
        int c0 = d_L6[blk - 1], c1 = d_L6[blk];
        acc = 0.0f;
        for (int cc = c0; cc < c1; cc++) {
          float A = se0 * GSUM((0 + rr) * 36 + cc) + se1 * GSUM((8 + rr) * 36 + cc) + se2 * GSUM((16 + rr) * 36 + cc);
          acc += d_NM[cc] * A * A;
        }
      }
      fout[u] = acc;
    }
    #undef GSUM
    #pragma unroll
    for (int u = 0; u < 3; u++) sFeat[lane + 64 * u] = fout[u];

    // MLP layer 1: 192 -> 64
    {
      float a0 = 0.f, a1 = 0.f, a2 = 0.f, a3 = 0.f;
      for (int k4 = 0; k4 < 48; k4++) {
        float4 f4 = *(const float4*)(sFeat + k4 * 4);
        const float* w = Wa1 + (k4 * 4) * 64 + lane;
        a0 += f4.x * w[0];
        a1 += f4.y * w[64];
        a2 += f4.z * w[128];
        a3 += f4.w * w[192];
      }
      sH[lane] = siluf(a0 + a1 + a2 + a3 + ba1[lane]);
    }

    // MLP layer 2: 64 -> 64, then layer 3 + wave reduction
    {
      float a0 = 0.f, a1 = 0.f, a2 = 0.f, a3 = 0.f;
      for (int k4 = 0; k4 < 16; k4++) {
        float4 h4 = *(const float4*)(sH + k4 * 4);
        const float* w = Wa2 + (k4 * 4) * 64 + lane;
        a0 += h4.x * w[0];
        a1 += h4.y * w[64];
        a2 += h4.z * w[128];
        a3 += h4.w * w[192];
      }
      float h2 = siluf(a0 + a1 + a2 + a3 + ba2[lane]);
      float pr = h2 * Wa3[lane];
      #pragma unroll
      for (int off = 32; off > 0; off >>= 1) pr += __shfl_down(pr, off, 64);
      if (lane == 0) out[a] = pr + ba3[0];
    }
  }
}

extern "C" void kernel_launch(void* const* d_in, const int* in_sizes, int n_in,
                              void* d_out, int out_size, void* d_ws, size_t ws_size,
                              hipStream_t stream)
{
  const float* rij         = (const float*)d_in[0];
  const int*   species     = (const int*)  d_in[1];
  const int*   first_atom  = (const int*)  d_in[2];
  const int*   second_atom = (const int*)  d_in[3];
  const float* Wr1 = (const float*)d_in[4];
  const float* br1 = (const float*)d_in[5];
  const float* Wr2 = (const float*)d_in[6];
  const float* br2 = (const float*)d_in[7];
  const float* Ws1 = (const float*)d_in[8];
  const float* bs1 = (const float*)d_in[9];
  const float* Ws2 = (const float*)d_in[10];
  const float* bs2 = (const float*)d_in[11];
  const float* Wa1 = (const float*)d_in[12];
  const float* ba1 = (const float*)d_in[13];
  const float* Wa2 = (const float*)d_in[14];
  const float* ba2 = (const float*)d_in[15];
  const float* Wa3 = (const float*)d_in[16];
  const float* ba3 = (const float*)d_in[17];
  float* ws  = (float*)d_ws;
  float* out = (float*)d_out;

  k_init<<<(NBINS + 255) / 256, 256, 0, stream>>>(Ws1, bs1, Ws2, bs2, ws);
  k_hist<<<(NEDGES + 255) / 256, 256, 0, stream>>>(first_atom, second_atom, species, ws);
  k_alloc<<<(NATOMS + 255) / 256, 256, 0, stream>>>(ws);
  k_scatter<<<(NEDGES + 255) / 256, 256, 0, stream>>>(first_atom, second_atom, species, ws);
  k_edge<<<(NEDGES + 255) / 256, 256, 0, stream>>>(rij, Wr1, br1, Wr2, br2, ws);
  k_atom<<<NATOMS, 128, 0, stream>>>(ws, Wa1, ba1, Wa2, ba2, Wa3, ba3, out);
}

// Round 6
// 233.440 us; speedup vs baseline: 1.1299x; 1.1299x over previous
//
#include <hip/hip_runtime.h>
#include <math.h>

#define NATOMS 10000
#define NEDGES 320000
#define RC_F 5.0f
#define PI_F 3.14159265358979323846f

// ---- workspace layout (in floats) ----
#define WS_SEMB   0         // 12 floats
#define WS_GTOT   12        // 1 int global allocation cursor
#define WS_CNT    16        // NATOMS ints
#define WS_OFFS   10016     // NATOMS ints (run start per atom)
#define WS_CURSOR 20016     // NATOMS ints
#define WS_EIDX   30016     // NEDGES ints: packed (t<<20)|e per atom-run
#define WS_STAGE  350080    // NEDGES*64 floats, 256B records, slot = edge id (256B aligned)

// multinomial term tables (global component index 0..34)
__device__ __constant__ int   d_PWA[35] = {0, 0,0,1, 0,0,0,1,1,2, 0,0,0,0,1,1,1,2,2,3, 0,0,0,0,0,1,1,1,1,2,2,2,3,3,4};
__device__ __constant__ int   d_PWB[35] = {0, 0,1,0, 0,1,2,0,1,0, 0,1,2,3,0,1,2,0,1,0, 0,1,2,3,4,0,1,2,3,0,1,2,0,1,0};
__device__ __constant__ int   d_PWC[35] = {0, 1,0,0, 2,1,0,1,0,0, 3,2,1,0,2,1,0,1,0,0, 4,3,2,1,0,3,2,1,0,2,1,0,1,0,0};
__device__ __constant__ float d_NM[35]  = {1.f, 1.f,1.f,1.f, 1.f,2.f,1.f,2.f,2.f,1.f,
                                           1.f,3.f,3.f,1.f,3.f,6.f,3.f,3.f,3.f,1.f,
                                           1.f,4.f,6.f,4.f,1.f,4.f,12.f,12.f,4.f,6.f,12.f,6.f,4.f,4.f,1.f};
__device__ __constant__ int   d_LBLK[35]= {0, 1,1,1, 2,2,2,2,2,2, 3,3,3,3,3,3,3,3,3,3, 4,4,4,4,4,4,4,4,4,4,4,4,4,4,4};
__device__ __constant__ int   d_L6[6]   = {0,1,4,10,20,35};

__device__ __forceinline__ float siluf(float x) { return x / (1.0f + __expf(-x)); }

__device__ __forceinline__ float psel(float x, int p) {
  float x2 = x * x;
  float r = 1.0f;
  r = (p == 1) ? x : r;
  r = (p == 2) ? x2 : r;
  r = (p == 3) ? x2 * x : r;
  r = (p == 4) ? x2 * x2 : r;
  return r;
}

// ---------------- k_init ----------------
__global__ void k_init(const float* __restrict__ Ws1, const float* __restrict__ bs1,
                       const float* __restrict__ Ws2, const float* __restrict__ bs2,
                       float* __restrict__ ws)
{
  int tid = blockIdx.x * blockDim.x + threadIdx.x;
  int* cnt = (int*)(ws + WS_CNT);
  if (tid < NATOMS) cnt[tid] = 0;
  if (tid == 0) *(int*)(ws + WS_GTOT) = 0;
  if (tid < 12) {
    int t = tid >> 2, s = tid & 3;
    float acc = bs2[s];
    for (int j = 0; j < 16; j++) acc += tanhf(Ws1[t * 16 + j] + bs1[j]) * Ws2[j * 4 + s];
    ws[WS_SEMB + tid] = acc;
  }
}

// ---------------- k_hist: per-atom edge counts ----------------
__global__ void k_hist(const int* __restrict__ first_atom, float* __restrict__ ws)
{
  int e = blockIdx.x * blockDim.x + threadIdx.x;
  if (e < NEDGES) {
    int* cnt = (int*)(ws + WS_CNT);
    atomicAdd(&cnt[first_atom[e]], 1);
  }
}

// ---------------- k_alloc: decentralized run allocation (order-free) ----------------
__global__ __launch_bounds__(256) void k_alloc(float* __restrict__ ws)
{
  const int* cnt = (const int*)(ws + WS_CNT);
  int* offs   = (int*)(ws + WS_OFFS);
  int* cursor = (int*)(ws + WS_CURSOR);
  int* gtot = (int*)(ws + WS_GTOT);
  __shared__ int wsum[4];
  __shared__ int sbase;
  int tid = threadIdx.x;
  int lane = tid & 63, wv = tid >> 6;
  int a = blockIdx.x * 256 + tid;
  bool live = (a < NATOMS);
  int c = live ? cnt[a] : 0;
  int inc = c;
  #pragma unroll
  for (int d = 1; d < 64; d <<= 1) {
    int v = __shfl_up(inc, d, 64);
    if (lane >= d) inc += v;
  }
  if (lane == 63) wsum[wv] = inc;
  __syncthreads();
  if (tid == 0) sbase = atomicAdd(gtot, wsum[0] + wsum[1] + wsum[2] + wsum[3]);
  __syncthreads();
  int woff = sbase;
  for (int w = 0; w < wv; w++) woff += wsum[w];
  int o0 = woff + inc - c;
  if (live) { offs[a] = o0; cursor[a] = o0; }
}

// ---------------- k_edge: dense MLP + fused eidx scatter ----------------
// Record stored at OWN slot e (coalesced 256B-stride stores); only the 4-byte
// packed (species<<20|e) goes through the scattered path.
__global__ __launch_bounds__(256) void k_edge(
    const float* __restrict__ rij, const int* __restrict__ species,
    const int* __restrict__ first_atom, const int* __restrict__ second_atom,
    const float* __restrict__ Wr1, const float* __restrict__ br1,
    const float* __restrict__ Wr2, const float* __restrict__ br2,
    float* __restrict__ ws)
{
  int e = blockIdx.x * 256 + threadIdx.x;
  if (e >= NEDGES) return;
  float* stage = ws + WS_STAGE;
  int* cursor = (int*)(ws + WS_CURSOR);
  int* eidx   = (int*)(ws + WS_EIDX);

  // issue gather chain + atomic + eidx store early; latency overlaps the MLP
  int a = first_atom[e];
  int t = species[second_atom[e]];
  int pos = atomicAdd(&cursor[a], 1);
  eidx[pos] = e | (t << 20);

  float x = rij[e * 3 + 0], y = rij[e * 3 + 1], z = rij[e * 3 + 2];
  float d = sqrtf(x * x + y * y + z * z + 1e-12f);
  float invd = 1.0f / d;
  float fc = (d < RC_F) ? 0.5f * (__cosf(PI_F * d / RC_F) + 1.0f) : 0.0f;

  float bes[8];
  float sq = sqrtf(2.0f / RC_F);
  #pragma unroll
  for (int k = 0; k < 8; k++) bes[k] = sq * __sinf((float)(k + 1) * (PI_F / RC_F) * d) * invd;

  // layer 1: 8 -> 64 (Wr1 wave-uniform -> scalar loads)
  float h1[64];
  #pragma unroll
  for (int j4 = 0; j4 < 16; j4++) {
    float acc[4];
    #pragma unroll
    for (int u = 0; u < 4; u++) acc[u] = br1[j4 * 4 + u];
    #pragma unroll
    for (int k = 0; k < 8; k++) {
      #pragma unroll
      for (int u = 0; u < 4; u++) acc[u] += bes[k] * Wr1[k * 64 + j4 * 4 + u];
    }
    #pragma unroll
    for (int u = 0; u < 4; u++) h1[j4 * 4 + u] = siluf(acc[u]);
  }

  float* eb = stage + (size_t)e * 64;

  // layer 2: 64 -> 48 (Wr2 wave-uniform -> scalar loads)
  for (int j4 = 0; j4 < 12; j4++) {
    float acc[4];
    #pragma unroll
    for (int u = 0; u < 4; u++) acc[u] = br2[j4 * 4 + u];
    #pragma unroll
    for (int k = 0; k < 64; k++) {
      #pragma unroll
      for (int u = 0; u < 4; u++) acc[u] += h1[k] * Wr2[k * 48 + j4 * 4 + u];
    }
    float v0 = siluf(acc[0]) * fc, v1 = siluf(acc[1]) * fc;
    float v2 = siluf(acc[2]) * fc, v3 = siluf(acc[3]) * fc;
    *(float4*)(eb + j4 * 4) = make_float4(v0, v1, v2, v3);
  }
  *(float4*)(eb + 48) = make_float4(x * invd, y * invd, z * invd, 0.0f);
}

// ---------------- k_atom: one wave per atom, 16-lane/record LDS gather, no barriers ----------------
__global__ __launch_bounds__(128) void k_atom(
    const float* __restrict__ ws,
    const float* __restrict__ Wa1, const float* __restrict__ ba1,
    const float* __restrict__ Wa2, const float* __restrict__ ba2,
    const float* __restrict__ Wa3, const float* __restrict__ ba3,
    float* __restrict__ out)
{
  // per-wave: [0..511] double-buffered 4-record stage, [512..1375] G (col 35 = G0),
  //           [1376..1567] feat, [1568..1631] h
  __shared__ __align__(16) float sScr[2][1696];
  int tid = threadIdx.x;
  int lane = tid & 63, wv = tid >> 6;
  int a = blockIdx.x * 2 + wv;          // NATOMS = 5000*2 exact
  float* sStage = &sScr[wv][0];
  float* sG     = &sScr[wv][512];
  float* sFeat  = &sScr[wv][1376];
  float* sH     = &sScr[wv][1568];

  const int* offs = (const int*)(ws + WS_OFFS);
  const int* cnt  = (const int*)(ws + WS_CNT);
  const int* eidx = (const int*)(ws + WS_EIDX);
  const float* stage = ws + WS_STAGE;
  int start = offs[a], len = cnt[a], end = start + len;

  const int c = lane;
  bool isc = (c < 35);
  int pa = 0, pb = 0, pcw = 0, lb = 0;
  if (isc) { pa = d_PWA[c]; pb = d_PWB[c]; pcw = d_PWC[c]; lb = d_LBLK[c]; }
  int rdir = lane - 35;
  bool isd = (rdir >= 0) && (rdir < 8);
  int rl = lane >> 4, fl = lane & 15;   // gather role: record rl, float4 fl

  float gc[3][8];
  #pragma unroll
  for (int t2 = 0; t2 < 3; t2++)
    #pragma unroll
    for (int r = 0; r < 8; r++) gc[t2][r] = 0.0f;
  float g0[3] = {0.0f, 0.0f, 0.0f};

#define CORE(T)                                                               \
  if (isc) {                                                                  \
    float4 rt = *(const float4*)(rb + 48);                                    \
    float comp = psel(rt.x, pa) * psel(rt.y, pb) * psel(rt.z, pcw);           \
    float4 Ra = *(const float4*)(rb + 8 + 8 * lb);                            \
    float4 Rb = *(const float4*)(rb + 12 + 8 * lb);                           \
    gc[T][0] += comp * Ra.x; gc[T][1] += comp * Ra.y;                         \
    gc[T][2] += comp * Ra.z; gc[T][3] += comp * Ra.w;                         \
    gc[T][4] += comp * Rb.x; gc[T][5] += comp * Rb.y;                         \
    gc[T][6] += comp * Rb.z; gc[T][7] += comp * Rb.w;                         \
  } else if (isd) {                                                           \
    g0[T] += rb[rdir];                                                        \
  }

  for (int cb = start; cb < end; cb += 64) {
    int m = end - cb; if (m > 64) m = 64;
    int pp = cb + lane;
    int packed = eidx[pp < end ? pp : start];     // coalesced chunk of indices
    // prefetch round 0 (4 records, 16 lanes each -> 8 full cache lines)
    int sl = rl; if (sl >= m) sl = m - 1;
    int pk = __shfl(packed, sl, 64);
    float4 v = *(const float4*)(stage + (size_t)(pk & 0xFFFFF) * 64 + fl * 4);
    for (int g = 0; g < m; g += 4) {
      float* buf = sStage + (((g >> 2) & 1) << 8);
      *(float4*)(buf + rl * 64 + fl * 4) = v;     // ds_write staged round
      if (g + 4 < m) {                            // prefetch next round into regs
        int sl2 = g + 4 + rl; if (sl2 >= m) sl2 = m - 1;
        int pk2 = __shfl(packed, sl2, 64);
        v = *(const float4*)(stage + (size_t)(pk2 & 0xFFFFF) * 64 + fl * 4);
      }
      int gm = m - g; if (gm > 4) gm = 4;
      for (int j = 0; j < gm; j++) {
        int t = __shfl(packed, g + j, 64) >> 20;  // wave-uniform species
        const float* rb = buf + j * 64;
        if (t == 0)      { CORE(0) }
        else if (t == 1) { CORE(1) }
        else             { CORE(2) }
      }
    }
  }
#undef CORE

  // transpose G into LDS (same-wave, no barrier)
  if (isc) {
    #pragma unroll
    for (int t2 = 0; t2 < 3; t2++)
      #pragma unroll
      for (int r = 0; r < 8; r++) sG[(t2 * 8 + r) * 36 + c] = gc[t2][r];
  } else if (isd) {
    #pragma unroll
    for (int t2 = 0; t2 < 3; t2++) sG[(t2 * 8 + rdir) * 36 + 35] = g0[t2];
  }

  // contraction: lane owns feats {lane, lane+64, lane+128}; f=(blk*8+rr)*4+s
  int s = lane & 3;
  float se0 = ws[WS_SEMB + s], se1 = ws[WS_SEMB + 4 + s], se2 = ws[WS_SEMB + 8 + s];
  float fout[3];
  #pragma unroll
  for (int u = 0; u < 3; u++) {
    int f = lane + 64 * u;
    int blk = f >> 5, rr = (f >> 2) & 7;
    float acc;
    if (blk == 0) {
      acc = se0 * sG[(0 + rr) * 36 + 35] + se1 * sG[(8 + rr) * 36 + 35] + se2 * sG[(16 + rr) * 36 + 35];
    } else {
      int c0 = d_L6[blk - 1], c1 = d_L6[blk];
      acc = 0.0f;
      for (int cc = c0; cc < c1; cc++) {
        float A = se0 * sG[(0 + rr) * 36 + cc] + se1 * sG[(8 + rr) * 36 + cc] + se2 * sG[(16 + rr) * 36 + cc];
        acc += d_NM[cc] * A * A;
      }
    }
    fout[u] = acc;
  }
  #pragma unroll
  for (int u = 0; u < 3; u++) sFeat[lane + 64 * u] = fout[u];

  // MLP layer 1: 192 -> 64
  {
    float a0 = 0.f, a1 = 0.f, a2 = 0.f, a3 = 0.f;
    for (int k4 = 0; k4 < 48; k4++) {
      float4 f4 = *(const float4*)(sFeat + k4 * 4);
      const float* w = Wa1 + (k4 * 4) * 64 + lane;
      a0 += f4.x * w[0];
      a1 += f4.y * w[64];
      a2 += f4.z * w[128];
      a3 += f4.w * w[192];
    }
    sH[lane] = siluf(a0 + a1 + a2 + a3 + ba1[lane]);
  }

  // MLP layer 2: 64 -> 64, layer 3 + wave reduction
  {
    float a0 = 0.f, a1 = 0.f, a2 = 0.f, a3 = 0.f;
    for (int k4 = 0; k4 < 16; k4++) {
      float4 h4 = *(const float4*)(sH + k4 * 4);
      const float* w = Wa2 + (k4 * 4) * 64 + lane;
      a0 += h4.x * w[0];
      a1 += h4.y * w[64];
      a2 += h4.z * w[128];
      a3 += h4.w * w[192];
    }
    float h2 = siluf(a0 + a1 + a2 + a3 + ba2[lane]);
    float pr = h2 * Wa3[lane];
    #pragma unroll
    for (int off = 32; off > 0; off >>= 1) pr += __shfl_down(pr, off, 64);
    if (lane == 0) out[a] = pr + ba3[0];
  }
}

extern "C" void kernel_launch(void* const* d_in, const int* in_sizes, int n_in,
                              void* d_out, int out_size, void* d_ws, size_t ws_size,
                              hipStream_t stream)
{
  const float* rij         = (const float*)d_in[0];
  const int*   species     = (const int*)  d_in[1];
  const int*   first_atom  = (const int*)  d_in[2];
  const int*   second_atom = (const int*)  d_in[3];
  const float* Wr1 = (const float*)d_in[4];
  const float* br1 = (const float*)d_in[5];
  const float* Wr2 = (const float*)d_in[6];
  const float* br2 = (const float*)d_in[7];
  const float* Ws1 = (const float*)d_in[8];
  const float* bs1 = (const float*)d_in[9];
  const float* Ws2 = (const float*)d_in[10];
  const float* bs2 = (const float*)d_in[11];
  const float* Wa1 = (const float*)d_in[12];
  const float* ba1 = (const float*)d_in[13];
  const float* Wa2 = (const float*)d_in[14];
  const float* ba2 = (const float*)d_in[15];
  const float* Wa3 = (const float*)d_in[16];
  const float* ba3 = (const float*)d_in[17];
  float* ws  = (float*)d_ws;
  float* out = (float*)d_out;

  k_init<<<40, 256, 0, stream>>>(Ws1, bs1, Ws2, bs2, ws);
  k_hist<<<(NEDGES + 255) / 256, 256, 0, stream>>>(first_atom, ws);
  k_alloc<<<40, 256, 0, stream>>>(ws);
  k_edge<<<(NEDGES + 255) / 256, 256, 0, stream>>>(rij, species, first_atom, second_atom,
                                                   Wr1, br1, Wr2, br2, ws);
  k_atom<<<NATOMS / 2, 128, 0, stream>>>(ws, Wa1, ba1, Wa2, ba2, Wa3, ba3, out);
}